// Round 15
// baseline (483.233 us; speedup 1.0000x reference)
//
#include <hip/hip_runtime.h>
#include <cmath>

// ---------------------------------------------------------------------------
// BrainAgeGATv2: 4-layer GATv2-ish GNN, N=40000 nodes, E=400000 edges, B=100
// graphs, hidden = H*C = 128.
// R14: 454.8us. gat pinned at ~49us across FETCH 107->55->49MB => NOT
//      traffic-bound; latency/issue-bound at Occ 52% (= lb(256,4)'s 16
//      waves/CU exactly).
// R15: SINGLE-VARIABLE: gat blocks 256->128 threads (2 nodes/block),
//      lb(128,8) (VGPR cap 64 >= 36 live, spill impossible). Finer block
//      granularity -> up to 32 waves/CU + no 4-wave retire imbalance.
//      Everything else identical to R14.
// ---------------------------------------------------------------------------

#define CAP 48
#define POOL_SPLIT 8

typedef __bf16 bf16x8 __attribute__((ext_vector_type(8)));
typedef float f32x4 __attribute__((ext_vector_type(4)));

__device__ inline unsigned pack_bf16(__bf16 a, __bf16 b) {
  union { __bf16 h; unsigned short u; } ua, ub;
  ua.h = a; ub.h = b;
  return ((unsigned)ub.u << 16) | ua.u;
}

// ---------------- fused prep: ea_sum | embed | w_pack ------------------------
// blocks [0,Ge): ea_sum reduction; [Ge,Ge+Gn): embed; [Ge+Gn,+512): w_pack.

__global__ __launch_bounds__(256) void prep_kernel(
    const float* __restrict__ eattr, float* __restrict__ ea_sum, int E,
    const float* __restrict__ x, const float* __restrict__ W_emb,
    const float* __restrict__ b_emb, __bf16* __restrict__ h0hi,
    __bf16* __restrict__ h0lo, int n, const float* __restrict__ Wl1,
    const float* __restrict__ Wr1, const float* __restrict__ Wl234,
    const float* __restrict__ Wr234, __bf16* __restrict__ wfHi,
    __bf16* __restrict__ wfLo, int Ge, int Gn) {
  __shared__ float red[256];
  int bid = blockIdx.x;
  if (bid < Ge) {
    // ---- ea_sum ----
    int i = bid * 256 + threadIdx.x;
    float v = (i < E) ? eattr[i] : 0.f;
    red[threadIdx.x] = v;
    __syncthreads();
    for (int off = 128; off > 0; off >>= 1) {
      if (threadIdx.x < off) red[threadIdx.x] += red[threadIdx.x + off];
      __syncthreads();
    }
    if (threadIdx.x == 0) atomicAdd(ea_sum, red[0]);
    return;
  }
  bid -= Ge;
  if (bid < Gn) {
    // ---- embed: h0 = relu(x @ W_emb + b_emb) -> bf16 hi/lo ----
    int idx = bid * 256 + threadIdx.x;
    if (idx >= n * 64) return;
    int v = idx >> 6, j = idx & 63;
    float s = b_emb[j];
    s += x[v * 4 + 0] * W_emb[j];
    s += x[v * 4 + 1] * W_emb[64 + j];
    s += x[v * 4 + 2] * W_emb[128 + j];
    s += x[v * 4 + 3] * W_emb[192 + j];
    s = fmaxf(s, 0.f);
    __bf16 hi = (__bf16)s;
    h0hi[idx] = hi;
    h0lo[idx] = (__bf16)(s - (float)hi);
    return;
  }
  bid -= Gn;
  // ---- w_pack: per-lane MFMA fragment order ----
  // wf element (L, g, n, ks, lane l, e) = hi/lo of W[k][col], where
  // k = ks*32 + (l>>4)*8 + e, col = g*64 + n*16 + (l&15)  (W=[Wl|Wr], KxC).
  int k = bid & 127;
  int L = bid >> 7;
  int col = threadIdx.x;
  int K = (L == 0) ? 64 : 128;
  if (k >= K) return;
  int KS = K >> 5;
  const float* Wl = (L == 0) ? Wl1 : Wl234 + (size_t)(L - 1) * 128 * 128;
  const float* Wr = (L == 0) ? Wr1 : Wr234 + (size_t)(L - 1) * 128 * 128;
  float v = (col < 128) ? Wl[k * 128 + col] : Wr[k * 128 + (col - 128)];
  __bf16 hi = (__bf16)v;
  __bf16 lo = (__bf16)(v - (float)hi);
  int g = col >> 6, nn = (col >> 4) & 3, cl = col & 15;
  int ks = k >> 5, sl = (k >> 3) & 3, e = k & 7;
  int l = sl * 16 + cl;
  size_t dst =
      (size_t)L * 256 * 128 + ((((size_t)(g * 4 + nn) * KS + ks) * 64 + l) * 8 + e);
  wfHi[dst] = hi;
  wfLo[dst] = lo;
}

// fill padded CSR: row v occupies csr[v*CAP .. v*CAP+cnt[v])
__global__ __launch_bounds__(256) void fill_kernel(const int* __restrict__ ei,
                                                   const float* __restrict__ eattr,
                                                   const float* __restrict__ ea_sum,
                                                   int* __restrict__ cnt,
                                                   int2* __restrict__ csr, int E, int n) {
  int i = blockIdx.x * 256 + threadIdx.x;
  if (i >= E + n) return;
  int s, d;
  float ev;
  if (i < E) {
    s = ei[i];
    d = ei[(size_t)E + i];
    ev = eattr[i];
  } else {
    s = d = i - E;                       // self loop
    ev = ea_sum[0] * (1.0f / (float)E);  // mean(edge_attr)
  }
  int pos = atomicAdd(&cnt[d], 1);
  if (pos < CAP) csr[(size_t)d * CAP + pos] = make_int2(s, __float_as_int(ev));
}

// ---------------- MFMA GEMM v3: no LDS, no barrier ---------------------------
// Split-bf16 (3 terms). Block 64M x 64N (4 waves, wave w = rows 16w..16w+15).
// A fragments: direct coalesced global reads (rows partitioned across waves).
// W fragments: pre-packed global, same address across blocks (L2-hot).
// XCD-bijective swizzle co-locates the 4 N-blocks sharing an A-panel.
// xl (cols 0-127) and xr (cols 128-255) both emitted as bf16.
// Fragment mapping (m89/m101-verified): a: lane l -> A[l%16][8*(l>>4)+e];
// b: lane l -> B[8*(l>>4)+e][l%16]; d: lane l, reg r -> D[4*(l>>4)+r][l%16].

__global__ __launch_bounds__(256) void gemm_mfma_kernel(
    const __bf16* __restrict__ hA, const __bf16* __restrict__ lA,
    const __bf16* __restrict__ wfHi, const __bf16* __restrict__ wfLo,
    const float* __restrict__ bl_l, const float* __restrict__ br_l,
    __bf16* __restrict__ xlb, __bf16* __restrict__ xrb, int K) {
  int t = threadIdx.x;
  // bijective XCD swizzle (m204): consecutive work ids -> same XCD
  int nwg = gridDim.x;
  int bid = blockIdx.x;
  int q8 = nwg >> 3, r8 = nwg & 7;
  int xcd = bid & 7, slot = bid >> 3;
  int wid = (xcd < r8 ? xcd * (q8 + 1) : r8 * (q8 + 1) + (xcd - r8) * q8) + slot;
  int g = wid & 3;           // 64-col slab (4 siblings share the A-panel)
  int n0 = g << 6;
  int r0 = (wid >> 2) << 6;  // M-tile
  int KS = K >> 5;

  int w = t >> 6, lane = t & 63;
  int arow = r0 + (w << 4) + (lane & 15);
  int kbb = (lane >> 4) << 4;  // byte offset of this lane's k-group in A row
  const char* pAhiG = (const char*)hA + (size_t)arow * (K << 1) + kbb;
  const char* pAloG = (const char*)lA + (size_t)arow * (K << 1) + kbb;
  const __bf16* wfH = wfHi + (size_t)(g * 4) * KS * 512 + lane * 8;
  const __bf16* wfL = wfLo + (size_t)(g * 4) * KS * 512 + lane * 8;

  f32x4 acc[4];
#pragma unroll
  for (int n = 0; n < 4; n++) acc[n] = (f32x4){0.f, 0.f, 0.f, 0.f};

  union U { uint4 u; bf16x8 b; };
  for (int ks = 0; ks < KS; ks++) {
    U ahi, alo;
    ahi.u = *(const uint4*)(pAhiG + (ks << 6));  // 64B per 32-k step
    alo.u = *(const uint4*)(pAloG + (ks << 6));
#pragma unroll
    for (int n = 0; n < 4; n++) {
      int wo = (n * KS + ks) << 9;  // *512 elements
      U bhi, blo;
      bhi.u = *(const uint4*)(wfH + wo);
      blo.u = *(const uint4*)(wfL + wo);
      acc[n] = __builtin_amdgcn_mfma_f32_16x16x32_bf16(ahi.b, bhi.b, acc[n], 0, 0, 0);
      acc[n] = __builtin_amdgcn_mfma_f32_16x16x32_bf16(ahi.b, blo.b, acc[n], 0, 0, 0);
      acc[n] = __builtin_amdgcn_mfma_f32_16x16x32_bf16(alo.b, bhi.b, acc[n], 0, 0, 0);
    }
  }

#pragma unroll
  for (int n = 0; n < 4; n++) {
    int col = n0 + (n << 4) + (lane & 15);
    float bv = (n0 < 128) ? bl_l[col & 127] : br_l[col & 127];
#pragma unroll
    for (int r = 0; r < 4; r++) {
      int row = r0 + (w << 4) + ((lane >> 4) << 2) + r;
      float val = acc[n][r] + bv;
      if (n0 < 128)
        xlb[(size_t)row * 128 + col] = (__bf16)val;
      else
        xrb[(size_t)row * 128 + (col - 128)] = (__bf16)val;
    }
  }
}

// ---------------- GAT aggregation: chunk-8, 128-thr blocks (R15) -------------
// R15: 2 nodes/block, lb(128,8) -> up to 32 waves/CU (was 16 at lb(256,4)),
// no 4-wave retire imbalance. Math and register plan identical to R14.

#define GAT_CHUNK 8

__global__ __launch_bounds__(128, 8) void gat_kernel(
    const __bf16* __restrict__ xlb, const __bf16* __restrict__ xrb,
    const int* __restrict__ cnt, const int2* __restrict__ csr,
    const float* __restrict__ We_l, const float* __restrict__ att_l,
    const float* __restrict__ bo_l, float* __restrict__ z, int n) {
  int wave = threadIdx.x >> 6;
  int lane = threadIdx.x & 63;
  int v = blockIdx.x * 2 + wave;
  if (v >= n) return;

  int c = lane * 2;  // channels c, c+1; head = c/16 = lane/8
  unsigned pxr = *reinterpret_cast<const unsigned*>(xrb + (size_t)v * 128 + c);
  float2 xrv;
  xrv.x = __uint_as_float(pxr << 16);
  xrv.y = __uint_as_float(pxr & 0xffff0000u);
  float2 wev = *reinterpret_cast<const float2*>(We_l + c);
  float2 atv = *reinterpret_cast<const float2*>(att_l + c);

  float m = -INFINITY, d = 0.f;
  float acc0 = 0.f, acc1 = 0.f;

  int beg = v * CAP;
  int end = beg + min(cnt[v], CAP);
  for (int base = beg; base < end; base += GAT_CHUNK) {
    int cnt8 = min(GAT_CHUNK, end - base);
    // wave-uniform metadata loads: all lanes hit the same cacheline
    int2 md[GAT_CHUNK];
#pragma unroll
    for (int j = 0; j < GAT_CHUNK; j++) {
      if (j >= cnt8) break;
      md[j] = csr[base + j];
    }
    // bf16x2 gathers, issued back-to-back (independent)
    float2 a[GAT_CHUNK];
#pragma unroll
    for (int j = 0; j < GAT_CHUNK; j++) {
      if (j >= cnt8) break;
      unsigned p = *reinterpret_cast<const unsigned*>(xlb + (size_t)md[j].x * 128 + c);
      a[j].x = __uint_as_float(p << 16);
      a[j].y = __uint_as_float(p & 0xffff0000u);
    }
    // scores: leaky_relu -> att dot -> 8-lane head reduce (3 shfl steps)
    float q[GAT_CHUNK];
#pragma unroll
    for (int j = 0; j < GAT_CHUNK; j++) {
      if (j >= cnt8) break;
      float ee = __int_as_float(md[j].y);
      float t0 = a[j].x + xrv.x + ee * wev.x;
      float t1 = a[j].y + xrv.y + ee * wev.y;
      t0 = (t0 >= 0.f) ? t0 : 0.2f * t0;  // leaky_relu
      t1 = (t1 >= 0.f) ? t1 : 0.2f * t1;
      float qq = t0 * atv.x + t1 * atv.y;
#pragma unroll
      for (int off = 1; off < 8; off <<= 1) qq += __shfl_xor(qq, off);
      q[j] = qq;
    }
    // chunk max + single rescale (exact exp(s - smax) semantics)
    float cm = -INFINITY;
#pragma unroll
    for (int j = 0; j < GAT_CHUNK; j++) {
      if (j >= cnt8) break;
      cm = fmaxf(cm, q[j]);
    }
    float nm = fmaxf(m, cm);
    float sc = __expf(m - nm);  // exp(-inf)=0 on the first chunk
    d *= sc;
    acc0 *= sc;
    acc1 *= sc;
#pragma unroll
    for (int j = 0; j < GAT_CHUNK; j++) {
      if (j >= cnt8) break;
      float e = __expf(q[j] - nm);
      d += e;
      acc0 += e * a[j].x;
      acc1 += e * a[j].y;
    }
    m = nm;
  }
  float inv = 1.f / (d + 1e-16f);
  float2 o;
  o.x = acc0 * inv + bo_l[c];
  o.y = acc1 * inv + bo_l[c + 1];
  *reinterpret_cast<float2*>(z + (size_t)v * 128 + c) = o;
}

// ---------------- BN: stats (float2) + final fused into apply ----------------

__global__ __launch_bounds__(256) void bn_stats_kernel(const float2* __restrict__ z2,
                                                       float* __restrict__ stats, int n) {
  int cp = threadIdx.x & 63;       // channel pair
  int quarter = threadIdx.x >> 6;  // 4 rows in parallel
  int chunk = (n + gridDim.x - 1) / gridDim.x;
  int v0 = blockIdx.x * chunk;
  int v1 = min(v0 + chunk, n);
  float s0 = 0.f, s1 = 0.f, q0 = 0.f, q1 = 0.f;
  for (int v = v0 + quarter; v < v1; v += 4) {
    float2 val = z2[(size_t)v * 64 + cp];
    s0 += val.x;
    q0 += val.x * val.x;
    s1 += val.y;
    q1 += val.y * val.y;
  }
  __shared__ float ls[4][128], lq[4][128];
  ls[quarter][cp * 2] = s0;
  ls[quarter][cp * 2 + 1] = s1;
  lq[quarter][cp * 2] = q0;
  lq[quarter][cp * 2 + 1] = q1;
  __syncthreads();
  if (threadIdx.x < 128) {
    int c = threadIdx.x;
    atomicAdd(&stats[c], ls[0][c] + ls[1][c] + ls[2][c] + ls[3][c]);
    atomicAdd(&stats[128 + c], lq[0][c] + lq[1][c] + lq[2][c] + lq[3][c]);
  }
}

__global__ __launch_bounds__(256) void bn_apply_kernel(
    const float2* __restrict__ z2, const float* __restrict__ stats_l,
    const float* __restrict__ gamma_l, const float* __restrict__ beta_l,
    unsigned* __restrict__ hhi2, unsigned* __restrict__ hlo2, int add_res, int n) {
  int i = blockIdx.x * 256 + threadIdx.x;  // channel-pair index
  if (i >= n * 64) return;
  int cp = (i & 63) * 2;
  float mean0 = stats_l[cp] / (float)n;
  float var0 = stats_l[128 + cp] / (float)n - mean0 * mean0;
  float sc0 = gamma_l[cp] * rsqrtf(var0 + 1e-5f);
  float off0 = beta_l[cp] - mean0 * sc0;
  float mean1 = stats_l[cp + 1] / (float)n;
  float var1 = stats_l[128 + cp + 1] / (float)n - mean1 * mean1;
  float sc1 = gamma_l[cp + 1] * rsqrtf(var1 + 1e-5f);
  float off1 = beta_l[cp + 1] - mean1 * sc1;

  float2 zz = z2[i];
  float v0 = zz.x * sc0 + off0;
  float v1 = zz.y * sc1 + off1;
  if (add_res) {
    unsigned ph = hhi2[i], pl = hlo2[i];
    v0 += __uint_as_float(ph << 16) + __uint_as_float(pl << 16);
    v1 += __uint_as_float(ph & 0xffff0000u) + __uint_as_float(pl & 0xffff0000u);
  }
  v0 = fmaxf(v0, 0.f);
  v1 = fmaxf(v1, 0.f);
  __bf16 h0 = (__bf16)v0, h1 = (__bf16)v1;
  __bf16 l0 = (__bf16)(v0 - (float)h0), l1 = (__bf16)(v1 - (float)h1);
  hhi2[i] = pack_bf16(h0, h1);
  hlo2[i] = pack_bf16(l0, l1);
}

// ---------------- pooling, two-stage (batch = repeat(arange(B), N/B)) --------

__global__ __launch_bounds__(256) void pool_partial_kernel(
    const unsigned* __restrict__ hhi2, const unsigned* __restrict__ hlo2,
    float* __restrict__ part, int npg) {
  int b = blockIdx.x, q = blockIdx.y;
  int half = threadIdx.x >> 6;  // 0..3 (4 rows in parallel)
  int cp = threadIdx.x & 63;    // channel pair
  int rows = npg / POOL_SPLIT;
  size_t base = ((size_t)b * npg + (size_t)q * rows) * 64;
  float s0 = 0.f, s1 = 0.f;
  for (int r = half; r < rows; r += 4) {
    unsigned uh = hhi2[base + (size_t)r * 64 + cp];
    unsigned ul = hlo2[base + (size_t)r * 64 + cp];
    s0 += __uint_as_float(uh << 16) + __uint_as_float(ul << 16);
    s1 += __uint_as_float(uh & 0xffff0000u) + __uint_as_float(ul & 0xffff0000u);
  }
  __shared__ float ls[4][128];
  ls[half][cp * 2] = s0;
  ls[half][cp * 2 + 1] = s1;
  __syncthreads();
  if (threadIdx.x < 128) {
    int c = threadIdx.x;
    part[((size_t)b * POOL_SPLIT + q) * 128 + c] =
        ls[0][c] + ls[1][c] + ls[2][c] + ls[3][c];
  }
}

// ---------------- fused MLP head ---------------------------------------------

__global__ __launch_bounds__(128) void final_mlp_kernel(
    const float* __restrict__ part, float inv_npg, const float* __restrict__ gf,
    const float* __restrict__ mW1, const float* __restrict__ mb1,
    const float* __restrict__ mW2, const float* __restrict__ mb2,
    const float* __restrict__ gW1, const float* __restrict__ gb1,
    const float* __restrict__ gW2, const float* __restrict__ gb2,
    const float* __restrict__ fW1, const float* __restrict__ fb1,
    const float* __restrict__ fW2, const float* __restrict__ fb2,
    const float* __restrict__ fW3, const float* __restrict__ fb3,
    float* __restrict__ out) {
  int b = blockIdx.x, t = threadIdx.x;
  __shared__ float s1[16], s2[16], s1b[16], s2b[16];
  __shared__ float zv[160], t1[128], t2[64];

  if (t < 16) {
    float s = mb1[t];
    for (int i = 0; i < 4; i++) s += gf[b * 6 + i] * mW1[i * 16 + t];
    s1[t] = fmaxf(s, 0.f);
  } else if (t < 32) {
    int j = t - 16;
    float s = gb1[j];
    for (int i = 0; i < 2; i++) s += gf[b * 6 + 4 + i] * gW1[i * 16 + j];
    s2[j] = fmaxf(s, 0.f);
  }
  {
    float ps = 0.f;
#pragma unroll
    for (int q = 0; q < POOL_SPLIT; q++)
      ps += part[((size_t)b * POOL_SPLIT + q) * 128 + t];
    zv[t] = ps * inv_npg;
  }
  __syncthreads();
  if (t < 16) {
    float s = mb2[t];
    for (int i = 0; i < 16; i++) s += s1[i] * mW2[i * 16 + t];
    s1b[t] = fmaxf(s, 0.f);
  } else if (t < 32) {
    int j = t - 16;
    float s = gb2[j];
    for (int i = 0; i < 16; i++) s += s2[i] * gW2[i * 16 + j];
    s2b[j] = fmaxf(s, 0.f);
  }
  __syncthreads();
  if (t < 16)
    zv[128 + t] = s1b[t];
  else if (t < 32)
    zv[128 + t] = s2b[t - 16];
  __syncthreads();
  {
    float s = fb1[t];
    for (int i = 0; i < 160; i++) s += zv[i] * fW1[i * 128 + t];
    t1[t] = fmaxf(s, 0.f);
  }
  __syncthreads();
  if (t < 64) {
    float s = fb2[t];
    for (int i = 0; i < 128; i++) s += t1[i] * fW2[i * 64 + t];
    t2[t] = fmaxf(s, 0.f);
  }
  __syncthreads();
  if (t == 0) {
    float s = fb3[0];
    for (int i = 0; i < 64; i++) s += t2[i] * fW3[i];
    out[b] = s;
  }
}

// ---------------- host launcher ----------------------------------------------

extern "C" void kernel_launch(void* const* d_in, const int* in_sizes, int n_in,
                              void* d_out, int out_size, void* d_ws, size_t ws_size,
                              hipStream_t stream) {
  const float* x = (const float*)d_in[0];
  const int* ei = (const int*)d_in[1];
  const float* eattr = (const float*)d_in[2];
  const float* gf = (const float*)d_in[4];
  const float* W_emb = (const float*)d_in[5];
  const float* b_emb = (const float*)d_in[6];
  const float* Wl1 = (const float*)d_in[7];
  const float* Wr1 = (const float*)d_in[8];
  const float* Wl234 = (const float*)d_in[9];
  const float* Wr234 = (const float*)d_in[10];
  const float* bl = (const float*)d_in[11];
  const float* br = (const float*)d_in[12];
  const float* We = (const float*)d_in[13];
  const float* att = (const float*)d_in[14];
  const float* bo = (const float*)d_in[15];
  const float* gamma = (const float*)d_in[16];
  const float* beta = (const float*)d_in[17];
  const float* mW1 = (const float*)d_in[18];
  const float* mb1 = (const float*)d_in[19];
  const float* mW2 = (const float*)d_in[20];
  const float* mb2 = (const float*)d_in[21];
  const float* gW1 = (const float*)d_in[22];
  const float* gb1 = (const float*)d_in[23];
  const float* gW2 = (const float*)d_in[24];
  const float* gb2 = (const float*)d_in[25];
  const float* fW1 = (const float*)d_in[26];
  const float* fb1 = (const float*)d_in[27];
  const float* fW2 = (const float*)d_in[28];
  const float* fb2 = (const float*)d_in[29];
  const float* fW3 = (const float*)d_in[30];
  const float* fb3 = (const float*)d_in[31];

  const int N = in_sizes[0] / 4;
  const int E = in_sizes[2];
  const int B = in_sizes[4] / 6;
  const int Ge = (E + 255) / 256;
  const int Gn = (N * 64 + 255) / 256;

  char* wsb = (char*)d_ws;
  size_t off = 0;
  auto alloc = [&](size_t bytes) {
    size_t r = off;
    off += (bytes + 255) & ~(size_t)255;
    return r;
  };
  // NOTE: cnt, ea_sum, stats contiguous -> single upfront memset.
  int* cnt = (int*)(wsb + alloc((size_t)N * 4));  // N*4 = 160000 (256-mult)
  float* ea_sum = (float*)(wsb + alloc(256));
  float* stats = (float*)(wsb + alloc(4 * 256 * 4));  // [L][256]
  size_t zero_bytes = (size_t)N * 4 + 256 + 4 * 256 * 4;

  float* z = (float*)(wsb + alloc((size_t)N * 128 * 4));
  __bf16* xrb = (__bf16*)(wsb + alloc((size_t)N * 128 * 2));
  __bf16* xlb = (__bf16*)(wsb + alloc((size_t)N * 128 * 2));
  __bf16* hhi = (__bf16*)(wsb + alloc((size_t)N * 128 * 2));
  __bf16* hlo = (__bf16*)(wsb + alloc((size_t)N * 128 * 2));
  __bf16* h0hi = (__bf16*)(wsb + alloc((size_t)N * 64 * 2));
  __bf16* h0lo = (__bf16*)(wsb + alloc((size_t)N * 64 * 2));
  __bf16* wfHi = (__bf16*)(wsb + alloc((size_t)4 * 256 * 128 * 2));
  __bf16* wfLo = (__bf16*)(wsb + alloc((size_t)4 * 256 * 128 * 2));
  int2* csr = (int2*)(wsb + alloc((size_t)N * CAP * 8));
  float* part = (float*)(wsb + alloc((size_t)B * POOL_SPLIT * 128 * 4));
  (void)ws_size;
  (void)n_in;
  (void)out_size;

  // ---- memset + fused prep (ea_sum | embed | w_pack) + CSR fill ----
  hipMemsetAsync(cnt, 0, zero_bytes, stream);
  prep_kernel<<<Ge + Gn + 512, 256, 0, stream>>>(eattr, ea_sum, E, x, W_emb, b_emb,
                                                 h0hi, h0lo, N, Wl1, Wr1, Wl234, Wr234,
                                                 wfHi, wfLo, Ge, Gn);
  fill_kernel<<<(E + N + 255) / 256, 256, 0, stream>>>(ei, eattr, ea_sum, cnt, csr, E,
                                                       N);

  // ---- 4 GAT layers ----
  for (int L = 0; L < 4; ++L) {
    int K = (L == 0) ? 64 : 128;
    const __bf16* hA = (L == 0) ? h0hi : hhi;
    const __bf16* lA = (L == 0) ? h0lo : hlo;

    gemm_mfma_kernel<<<4 * (N / 64), 256, 0, stream>>>(
        hA, lA, wfHi + (size_t)L * 256 * 128, wfLo + (size_t)L * 256 * 128,
        bl + L * 128, br + L * 128, xlb, xrb, K);
    gat_kernel<<<(N + 1) / 2, 128, 0, stream>>>(xlb, xrb, cnt, csr, We + L * 128,
                                                att + L * 128, bo + L * 128, z, N);
    bn_stats_kernel<<<256, 256, 0, stream>>>((const float2*)z, stats + L * 256, N);
    bn_apply_kernel<<<(N * 64 + 255) / 256, 256, 0, stream>>>(
        (const float2*)z, stats + L * 256, gamma + L * 128, beta + L * 128,
        (unsigned*)hhi, (unsigned*)hlo, (L == 0) ? 0 : 1, N);
  }

  // ---- pool + head ----
  pool_partial_kernel<<<dim3(B, POOL_SPLIT), 256, 0, stream>>>(
      (const unsigned*)hhi, (const unsigned*)hlo, part, N / B);
  final_mlp_kernel<<<B, 128, 0, stream>>>(part, (float)B / (float)N, gf, mW1, mb1, mW2,
                                          mb2, gW1, gb1, gW2, gb2, fW1, fb1, fW2, fb2,
                                          fW3, fb3, (float*)d_out);
}

// Round 17
// 465.870 us; speedup vs baseline: 1.0373x; 1.0373x over previous
//
#include <hip/hip_runtime.h>
#include <cmath>

// ---------------------------------------------------------------------------
// BrainAgeGATv2: 4-layer GATv2-ish GNN, N=40000 nodes, E=400000 edges, B=100
// graphs, hidden = H*C = 128.
// R14: 454.8us (best). gat chunk-8/lb(256,4)/VGPR36 = 49us.
// R15: gat lb(128,8) REGRESSED (VGPR 36->32, WRITE 20->56MB = mild spill;
//      3rd failed occupancy/traffic lever) => gat config FROZEN at R14.
// R16: revert gat to R14 exact; fuse pool_partial into bn_apply(L=3)
//      (4 nodes/block all in one graph; LDS reduce + 128 atomics/block,
//      ~100 adds/address). -1 dispatch, -pool kernel.
// R17: resubmit of R16 (container died before measuring).
// ---------------------------------------------------------------------------

#define CAP 48

typedef __bf16 bf16x8 __attribute__((ext_vector_type(8)));
typedef float f32x4 __attribute__((ext_vector_type(4)));

__device__ inline unsigned pack_bf16(__bf16 a, __bf16 b) {
  union { __bf16 h; unsigned short u; } ua, ub;
  ua.h = a; ub.h = b;
  return ((unsigned)ub.u << 16) | ua.u;
}

// ---------------- fused prep: ea_sum | embed | w_pack ------------------------
// blocks [0,Ge): ea_sum reduction; [Ge,Ge+Gn): embed; [Ge+Gn,+512): w_pack.

__global__ __launch_bounds__(256) void prep_kernel(
    const float* __restrict__ eattr, float* __restrict__ ea_sum, int E,
    const float* __restrict__ x, const float* __restrict__ W_emb,
    const float* __restrict__ b_emb, __bf16* __restrict__ h0hi,
    __bf16* __restrict__ h0lo, int n, const float* __restrict__ Wl1,
    const float* __restrict__ Wr1, const float* __restrict__ Wl234,
    const float* __restrict__ Wr234, __bf16* __restrict__ wfHi,
    __bf16* __restrict__ wfLo, int Ge, int Gn) {
  __shared__ float red[256];
  int bid = blockIdx.x;
  if (bid < Ge) {
    // ---- ea_sum ----
    int i = bid * 256 + threadIdx.x;
    float v = (i < E) ? eattr[i] : 0.f;
    red[threadIdx.x] = v;
    __syncthreads();
    for (int off = 128; off > 0; off >>= 1) {
      if (threadIdx.x < off) red[threadIdx.x] += red[threadIdx.x + off];
      __syncthreads();
    }
    if (threadIdx.x == 0) atomicAdd(ea_sum, red[0]);
    return;
  }
  bid -= Ge;
  if (bid < Gn) {
    // ---- embed: h0 = relu(x @ W_emb + b_emb) -> bf16 hi/lo ----
    int idx = bid * 256 + threadIdx.x;
    if (idx >= n * 64) return;
    int v = idx >> 6, j = idx & 63;
    float s = b_emb[j];
    s += x[v * 4 + 0] * W_emb[j];
    s += x[v * 4 + 1] * W_emb[64 + j];
    s += x[v * 4 + 2] * W_emb[128 + j];
    s += x[v * 4 + 3] * W_emb[192 + j];
    s = fmaxf(s, 0.f);
    __bf16 hi = (__bf16)s;
    h0hi[idx] = hi;
    h0lo[idx] = (__bf16)(s - (float)hi);
    return;
  }
  bid -= Gn;
  // ---- w_pack: per-lane MFMA fragment order ----
  // wf element (L, g, n, ks, lane l, e) = hi/lo of W[k][col], where
  // k = ks*32 + (l>>4)*8 + e, col = g*64 + n*16 + (l&15)  (W=[Wl|Wr], KxC).
  int k = bid & 127;
  int L = bid >> 7;
  int col = threadIdx.x;
  int K = (L == 0) ? 64 : 128;
  if (k >= K) return;
  int KS = K >> 5;
  const float* Wl = (L == 0) ? Wl1 : Wl234 + (size_t)(L - 1) * 128 * 128;
  const float* Wr = (L == 0) ? Wr1 : Wr234 + (size_t)(L - 1) * 128 * 128;
  float v = (col < 128) ? Wl[k * 128 + col] : Wr[k * 128 + (col - 128)];
  __bf16 hi = (__bf16)v;
  __bf16 lo = (__bf16)(v - (float)hi);
  int g = col >> 6, nn = (col >> 4) & 3, cl = col & 15;
  int ks = k >> 5, sl = (k >> 3) & 3, e = k & 7;
  int l = sl * 16 + cl;
  size_t dst =
      (size_t)L * 256 * 128 + ((((size_t)(g * 4 + nn) * KS + ks) * 64 + l) * 8 + e);
  wfHi[dst] = hi;
  wfLo[dst] = lo;
}

// fill padded CSR: row v occupies csr[v*CAP .. v*CAP+cnt[v])
__global__ __launch_bounds__(256) void fill_kernel(const int* __restrict__ ei,
                                                   const float* __restrict__ eattr,
                                                   const float* __restrict__ ea_sum,
                                                   int* __restrict__ cnt,
                                                   int2* __restrict__ csr, int E, int n) {
  int i = blockIdx.x * 256 + threadIdx.x;
  if (i >= E + n) return;
  int s, d;
  float ev;
  if (i < E) {
    s = ei[i];
    d = ei[(size_t)E + i];
    ev = eattr[i];
  } else {
    s = d = i - E;                       // self loop
    ev = ea_sum[0] * (1.0f / (float)E);  // mean(edge_attr)
  }
  int pos = atomicAdd(&cnt[d], 1);
  if (pos < CAP) csr[(size_t)d * CAP + pos] = make_int2(s, __float_as_int(ev));
}

// ---------------- MFMA GEMM v3: no LDS, no barrier ---------------------------
// Split-bf16 (3 terms). Block 64M x 64N (4 waves, wave w = rows 16w..16w+15).
// A fragments: direct coalesced global reads (rows partitioned across waves).
// W fragments: pre-packed global, same address across blocks (L2-hot).
// XCD-bijective swizzle co-locates the 4 N-blocks sharing an A-panel.
// xl (cols 0-127) and xr (cols 128-255) both emitted as bf16.
// Fragment mapping (m89/m101-verified): a: lane l -> A[l%16][8*(l>>4)+e];
// b: lane l -> B[8*(l>>4)+e][l%16]; d: lane l, reg r -> D[4*(l>>4)+r][l%16].

__global__ __launch_bounds__(256) void gemm_mfma_kernel(
    const __bf16* __restrict__ hA, const __bf16* __restrict__ lA,
    const __bf16* __restrict__ wfHi, const __bf16* __restrict__ wfLo,
    const float* __restrict__ bl_l, const float* __restrict__ br_l,
    __bf16* __restrict__ xlb, __bf16* __restrict__ xrb, int K) {
  int t = threadIdx.x;
  // bijective XCD swizzle (m204): consecutive work ids -> same XCD
  int nwg = gridDim.x;
  int bid = blockIdx.x;
  int q8 = nwg >> 3, r8 = nwg & 7;
  int xcd = bid & 7, slot = bid >> 3;
  int wid = (xcd < r8 ? xcd * (q8 + 1) : r8 * (q8 + 1) + (xcd - r8) * q8) + slot;
  int g = wid & 3;           // 64-col slab (4 siblings share the A-panel)
  int n0 = g << 6;
  int r0 = (wid >> 2) << 6;  // M-tile
  int KS = K >> 5;

  int w = t >> 6, lane = t & 63;
  int arow = r0 + (w << 4) + (lane & 15);
  int kbb = (lane >> 4) << 4;  // byte offset of this lane's k-group in A row
  const char* pAhiG = (const char*)hA + (size_t)arow * (K << 1) + kbb;
  const char* pAloG = (const char*)lA + (size_t)arow * (K << 1) + kbb;
  const __bf16* wfH = wfHi + (size_t)(g * 4) * KS * 512 + lane * 8;
  const __bf16* wfL = wfLo + (size_t)(g * 4) * KS * 512 + lane * 8;

  f32x4 acc[4];
#pragma unroll
  for (int n = 0; n < 4; n++) acc[n] = (f32x4){0.f, 0.f, 0.f, 0.f};

  union U { uint4 u; bf16x8 b; };
  for (int ks = 0; ks < KS; ks++) {
    U ahi, alo;
    ahi.u = *(const uint4*)(pAhiG + (ks << 6));  // 64B per 32-k step
    alo.u = *(const uint4*)(pAloG + (ks << 6));
#pragma unroll
    for (int n = 0; n < 4; n++) {
      int wo = (n * KS + ks) << 9;  // *512 elements
      U bhi, blo;
      bhi.u = *(const uint4*)(wfH + wo);
      blo.u = *(const uint4*)(wfL + wo);
      acc[n] = __builtin_amdgcn_mfma_f32_16x16x32_bf16(ahi.b, bhi.b, acc[n], 0, 0, 0);
      acc[n] = __builtin_amdgcn_mfma_f32_16x16x32_bf16(ahi.b, blo.b, acc[n], 0, 0, 0);
      acc[n] = __builtin_amdgcn_mfma_f32_16x16x32_bf16(alo.b, bhi.b, acc[n], 0, 0, 0);
    }
  }

#pragma unroll
  for (int n = 0; n < 4; n++) {
    int col = n0 + (n << 4) + (lane & 15);
    float bv = (n0 < 128) ? bl_l[col & 127] : br_l[col & 127];
#pragma unroll
    for (int r = 0; r < 4; r++) {
      int row = r0 + (w << 4) + ((lane >> 4) << 2) + r;
      float val = acc[n][r] + bv;
      if (n0 < 128)
        xlb[(size_t)row * 128 + col] = (__bf16)val;
      else
        xrb[(size_t)row * 128 + (col - 128)] = (__bf16)val;
    }
  }
}

// ---------------- GAT aggregation: R14-verified chunk-8, lb(256,4), FROZEN ---

#define GAT_CHUNK 8

__global__ __launch_bounds__(256, 4) void gat_kernel(
    const __bf16* __restrict__ xlb, const __bf16* __restrict__ xrb,
    const int* __restrict__ cnt, const int2* __restrict__ csr,
    const float* __restrict__ We_l, const float* __restrict__ att_l,
    const float* __restrict__ bo_l, float* __restrict__ z, int n) {
  int wave = threadIdx.x >> 6;
  int lane = threadIdx.x & 63;
  int v = blockIdx.x * 4 + wave;
  if (v >= n) return;

  int c = lane * 2;  // channels c, c+1; head = c/16 = lane/8
  unsigned pxr = *reinterpret_cast<const unsigned*>(xrb + (size_t)v * 128 + c);
  float2 xrv;
  xrv.x = __uint_as_float(pxr << 16);
  xrv.y = __uint_as_float(pxr & 0xffff0000u);
  float2 wev = *reinterpret_cast<const float2*>(We_l + c);
  float2 atv = *reinterpret_cast<const float2*>(att_l + c);

  float m = -INFINITY, d = 0.f;
  float acc0 = 0.f, acc1 = 0.f;

  int beg = v * CAP;
  int end = beg + min(cnt[v], CAP);
  for (int base = beg; base < end; base += GAT_CHUNK) {
    int cnt8 = min(GAT_CHUNK, end - base);
    // wave-uniform metadata loads: all lanes hit the same cacheline
    int2 md[GAT_CHUNK];
#pragma unroll
    for (int j = 0; j < GAT_CHUNK; j++) {
      if (j >= cnt8) break;
      md[j] = csr[base + j];
    }
    // bf16x2 gathers, issued back-to-back (independent)
    float2 a[GAT_CHUNK];
#pragma unroll
    for (int j = 0; j < GAT_CHUNK; j++) {
      if (j >= cnt8) break;
      unsigned p = *reinterpret_cast<const unsigned*>(xlb + (size_t)md[j].x * 128 + c);
      a[j].x = __uint_as_float(p << 16);
      a[j].y = __uint_as_float(p & 0xffff0000u);
    }
    // scores: leaky_relu -> att dot -> 8-lane head reduce (3 shfl steps)
    float q[GAT_CHUNK];
#pragma unroll
    for (int j = 0; j < GAT_CHUNK; j++) {
      if (j >= cnt8) break;
      float ee = __int_as_float(md[j].y);
      float t0 = a[j].x + xrv.x + ee * wev.x;
      float t1 = a[j].y + xrv.y + ee * wev.y;
      t0 = (t0 >= 0.f) ? t0 : 0.2f * t0;  // leaky_relu
      t1 = (t1 >= 0.f) ? t1 : 0.2f * t1;
      float qq = t0 * atv.x + t1 * atv.y;
#pragma unroll
      for (int off = 1; off < 8; off <<= 1) qq += __shfl_xor(qq, off);
      q[j] = qq;
    }
    // chunk max + single rescale (exact exp(s - smax) semantics)
    float cm = -INFINITY;
#pragma unroll
    for (int j = 0; j < GAT_CHUNK; j++) {
      if (j >= cnt8) break;
      cm = fmaxf(cm, q[j]);
    }
    float nm = fmaxf(m, cm);
    float sc = __expf(m - nm);  // exp(-inf)=0 on the first chunk
    d *= sc;
    acc0 *= sc;
    acc1 *= sc;
#pragma unroll
    for (int j = 0; j < GAT_CHUNK; j++) {
      if (j >= cnt8) break;
      float e = __expf(q[j] - nm);
      d += e;
      acc0 += e * a[j].x;
      acc1 += e * a[j].y;
    }
    m = nm;
  }
  float inv = 1.f / (d + 1e-16f);
  float2 o;
  o.x = acc0 * inv + bo_l[c];
  o.y = acc1 * inv + bo_l[c + 1];
  *reinterpret_cast<float2*>(z + (size_t)v * 128 + c) = o;
}

// ---------------- BN: stats (float2) + final fused into apply ----------------

__global__ __launch_bounds__(256) void bn_stats_kernel(const float2* __restrict__ z2,
                                                       float* __restrict__ stats, int n) {
  int cp = threadIdx.x & 63;       // channel pair
  int quarter = threadIdx.x >> 6;  // 4 rows in parallel
  int chunk = (n + gridDim.x - 1) / gridDim.x;
  int v0 = blockIdx.x * chunk;
  int v1 = min(v0 + chunk, n);
  float s0 = 0.f, s1 = 0.f, q0 = 0.f, q1 = 0.f;
  for (int v = v0 + quarter; v < v1; v += 4) {
    float2 val = z2[(size_t)v * 64 + cp];
    s0 += val.x;
    q0 += val.x * val.x;
    s1 += val.y;
    q1 += val.y * val.y;
  }
  __shared__ float ls[4][128], lq[4][128];
  ls[quarter][cp * 2] = s0;
  ls[quarter][cp * 2 + 1] = s1;
  lq[quarter][cp * 2] = q0;
  lq[quarter][cp * 2 + 1] = q1;
  __syncthreads();
  if (threadIdx.x < 128) {
    int c = threadIdx.x;
    atomicAdd(&stats[c], ls[0][c] + ls[1][c] + ls[2][c] + ls[3][c]);
    atomicAdd(&stats[128 + c], lq[0][c] + lq[1][c] + lq[2][c] + lq[3][c]);
  }
}

// bn_apply; for the last layer (do_pool=1) also accumulates per-graph channel
// sums into part[B][128] (block = 4 nodes, all in one graph since 400%4==0).
__global__ __launch_bounds__(256) void bn_apply_kernel(
    const float2* __restrict__ z2, const float* __restrict__ stats_l,
    const float* __restrict__ gamma_l, const float* __restrict__ beta_l,
    unsigned* __restrict__ hhi2, unsigned* __restrict__ hlo2, int add_res,
    int do_pool, float* __restrict__ part, int npg, int n) {
  int i = blockIdx.x * 256 + threadIdx.x;  // channel-pair index
  int cp = (i & 63) * 2;
  float v0 = 0.f, v1 = 0.f;
  if (i < n * 64) {
    float mean0 = stats_l[cp] / (float)n;
    float var0 = stats_l[128 + cp] / (float)n - mean0 * mean0;
    float sc0 = gamma_l[cp] * rsqrtf(var0 + 1e-5f);
    float off0 = beta_l[cp] - mean0 * sc0;
    float mean1 = stats_l[cp + 1] / (float)n;
    float var1 = stats_l[128 + cp + 1] / (float)n - mean1 * mean1;
    float sc1 = gamma_l[cp + 1] * rsqrtf(var1 + 1e-5f);
    float off1 = beta_l[cp + 1] - mean1 * sc1;

    float2 zz = z2[i];
    v0 = zz.x * sc0 + off0;
    v1 = zz.y * sc1 + off1;
    if (add_res) {
      unsigned ph = hhi2[i], pl = hlo2[i];
      v0 += __uint_as_float(ph << 16) + __uint_as_float(pl << 16);
      v1 += __uint_as_float(ph & 0xffff0000u) + __uint_as_float(pl & 0xffff0000u);
    }
    v0 = fmaxf(v0, 0.f);
    v1 = fmaxf(v1, 0.f);
    __bf16 h0 = (__bf16)v0, h1 = (__bf16)v1;
    __bf16 l0 = (__bf16)(v0 - (float)h0), l1 = (__bf16)(v1 - (float)h1);
    hhi2[i] = pack_bf16(h0, h1);
    hlo2[i] = pack_bf16(l0, l1);
  }
  if (do_pool) {
    __shared__ float ps[128];
    if (threadIdx.x < 128) ps[threadIdx.x] = 0.f;
    __syncthreads();
    atomicAdd(&ps[cp], v0);      // LDS atomics: 4 nodes contend per channel
    atomicAdd(&ps[cp + 1], v1);
    __syncthreads();
    if (threadIdx.x < 128) {
      int b = (blockIdx.x * 4) / npg;  // all 4 nodes of this block in graph b
      atomicAdd(&part[b * 128 + threadIdx.x], ps[threadIdx.x]);
    }
  }
}

// ---------------- fused MLP head (reads summed part directly) ----------------

__global__ __launch_bounds__(128) void final_mlp_kernel(
    const float* __restrict__ part, float inv_npg, const float* __restrict__ gf,
    const float* __restrict__ mW1, const float* __restrict__ mb1,
    const float* __restrict__ mW2, const float* __restrict__ mb2,
    const float* __restrict__ gW1, const float* __restrict__ gb1,
    const float* __restrict__ gW2, const float* __restrict__ gb2,
    const float* __restrict__ fW1, const float* __restrict__ fb1,
    const float* __restrict__ fW2, const float* __restrict__ fb2,
    const float* __restrict__ fW3, const float* __restrict__ fb3,
    float* __restrict__ out) {
  int b = blockIdx.x, t = threadIdx.x;
  __shared__ float s1[16], s2[16], s1b[16], s2b[16];
  __shared__ float zv[160], t1[128], t2[64];

  if (t < 16) {
    float s = mb1[t];
    for (int i = 0; i < 4; i++) s += gf[b * 6 + i] * mW1[i * 16 + t];
    s1[t] = fmaxf(s, 0.f);
  } else if (t < 32) {
    int j = t - 16;
    float s = gb1[j];
    for (int i = 0; i < 2; i++) s += gf[b * 6 + 4 + i] * gW1[i * 16 + j];
    s2[j] = fmaxf(s, 0.f);
  }
  zv[t] = part[b * 128 + t] * inv_npg;  // mean = sum / npg
  __syncthreads();
  if (t < 16) {
    float s = mb2[t];
    for (int i = 0; i < 16; i++) s += s1[i] * mW2[i * 16 + t];
    s1b[t] = fmaxf(s, 0.f);
  } else if (t < 32) {
    int j = t - 16;
    float s = gb2[j];
    for (int i = 0; i < 16; i++) s += s2[i] * gW2[i * 16 + j];
    s2b[j] = fmaxf(s, 0.f);
  }
  __syncthreads();
  if (t < 16)
    zv[128 + t] = s1b[t];
  else if (t < 32)
    zv[128 + t] = s2b[t - 16];
  __syncthreads();
  {
    float s = fb1[t];
    for (int i = 0; i < 160; i++) s += zv[i] * fW1[i * 128 + t];
    t1[t] = fmaxf(s, 0.f);
  }
  __syncthreads();
  if (t < 64) {
    float s = fb2[t];
    for (int i = 0; i < 128; i++) s += t1[i] * fW2[i * 64 + t];
    t2[t] = fmaxf(s, 0.f);
  }
  __syncthreads();
  if (t == 0) {
    float s = fb3[0];
    for (int i = 0; i < 64; i++) s += t2[i] * fW3[i];
    out[b] = s;
  }
}

// ---------------- host launcher ----------------------------------------------

extern "C" void kernel_launch(void* const* d_in, const int* in_sizes, int n_in,
                              void* d_out, int out_size, void* d_ws, size_t ws_size,
                              hipStream_t stream) {
  const float* x = (const float*)d_in[0];
  const int* ei = (const int*)d_in[1];
  const float* eattr = (const float*)d_in[2];
  const float* gf = (const float*)d_in[4];
  const float* W_emb = (const float*)d_in[5];
  const float* b_emb = (const float*)d_in[6];
  const float* Wl1 = (const float*)d_in[7];
  const float* Wr1 = (const float*)d_in[8];
  const float* Wl234 = (const float*)d_in[9];
  const float* Wr234 = (const float*)d_in[10];
  const float* bl = (const float*)d_in[11];
  const float* br = (const float*)d_in[12];
  const float* We = (const float*)d_in[13];
  const float* att = (const float*)d_in[14];
  const float* bo = (const float*)d_in[15];
  const float* gamma = (const float*)d_in[16];
  const float* beta = (const float*)d_in[17];
  const float* mW1 = (const float*)d_in[18];
  const float* mb1 = (const float*)d_in[19];
  const float* mW2 = (const float*)d_in[20];
  const float* mb2 = (const float*)d_in[21];
  const float* gW1 = (const float*)d_in[22];
  const float* gb1 = (const float*)d_in[23];
  const float* gW2 = (const float*)d_in[24];
  const float* gb2 = (const float*)d_in[25];
  const float* fW1 = (const float*)d_in[26];
  const float* fb1 = (const float*)d_in[27];
  const float* fW2 = (const float*)d_in[28];
  const float* fb2 = (const float*)d_in[29];
  const float* fW3 = (const float*)d_in[30];
  const float* fb3 = (const float*)d_in[31];

  const int N = in_sizes[0] / 4;
  const int E = in_sizes[2];
  const int B = in_sizes[4] / 6;
  const int Ge = (E + 255) / 256;
  const int Gn = (N * 64 + 255) / 256;

  char* wsb = (char*)d_ws;
  size_t off = 0;
  auto alloc = [&](size_t bytes) {
    size_t r = off;
    off += (bytes + 255) & ~(size_t)255;
    return r;
  };
  // NOTE: cnt, ea_sum, stats, part contiguous -> single upfront memset.
  int* cnt = (int*)(wsb + alloc((size_t)N * 4));  // N*4 = 160000 (256-mult)
  float* ea_sum = (float*)(wsb + alloc(256));
  float* stats = (float*)(wsb + alloc(4 * 256 * 4));       // [L][256]
  float* part = (float*)(wsb + alloc((size_t)B * 128 * 4));  // pooled sums
  size_t zero_bytes = (size_t)N * 4 + 256 + 4 * 256 * 4 + (size_t)B * 128 * 4;

  float* z = (float*)(wsb + alloc((size_t)N * 128 * 4));
  __bf16* xrb = (__bf16*)(wsb + alloc((size_t)N * 128 * 2));
  __bf16* xlb = (__bf16*)(wsb + alloc((size_t)N * 128 * 2));
  __bf16* hhi = (__bf16*)(wsb + alloc((size_t)N * 128 * 2));
  __bf16* hlo = (__bf16*)(wsb + alloc((size_t)N * 128 * 2));
  __bf16* h0hi = (__bf16*)(wsb + alloc((size_t)N * 64 * 2));
  __bf16* h0lo = (__bf16*)(wsb + alloc((size_t)N * 64 * 2));
  __bf16* wfHi = (__bf16*)(wsb + alloc((size_t)4 * 256 * 128 * 2));
  __bf16* wfLo = (__bf16*)(wsb + alloc((size_t)4 * 256 * 128 * 2));
  int2* csr = (int2*)(wsb + alloc((size_t)N * CAP * 8));
  (void)ws_size;
  (void)n_in;
  (void)out_size;

  // ---- memset + fused prep (ea_sum | embed | w_pack) + CSR fill ----
  hipMemsetAsync(cnt, 0, zero_bytes, stream);
  prep_kernel<<<Ge + Gn + 512, 256, 0, stream>>>(eattr, ea_sum, E, x, W_emb, b_emb,
                                                 h0hi, h0lo, N, Wl1, Wr1, Wl234, Wr234,
                                                 wfHi, wfLo, Ge, Gn);
  fill_kernel<<<(E + N + 255) / 256, 256, 0, stream>>>(ei, eattr, ea_sum, cnt, csr, E,
                                                       N);

  // ---- 4 GAT layers ----
  for (int L = 0; L < 4; ++L) {
    int K = (L == 0) ? 64 : 128;
    const __bf16* hA = (L == 0) ? h0hi : hhi;
    const __bf16* lA = (L == 0) ? h0lo : hlo;

    gemm_mfma_kernel<<<4 * (N / 64), 256, 0, stream>>>(
        hA, lA, wfHi + (size_t)L * 256 * 128, wfLo + (size_t)L * 256 * 128,
        bl + L * 128, br + L * 128, xlb, xrb, K);
    gat_kernel<<<(N + 3) / 4, 256, 0, stream>>>(xlb, xrb, cnt, csr, We + L * 128,
                                                att + L * 128, bo + L * 128, z, N);
    bn_stats_kernel<<<256, 256, 0, stream>>>((const float2*)z, stats + L * 256, N);
    bn_apply_kernel<<<(N * 64 + 255) / 256, 256, 0, stream>>>(
        (const float2*)z, stats + L * 256, gamma + L * 128, beta + L * 128,
        (unsigned*)hhi, (unsigned*)hlo, (L == 0) ? 0 : 1, (L == 3) ? 1 : 0, part,
        N / B, N);
  }

  // ---- head (pool fused into last bn_apply) ----
  final_mlp_kernel<<<B, 128, 0, stream>>>(part, (float)B / (float)N, gf, mW1, mb1, mW2,
                                          mb2, gW1, gb1, gW2, gb2, fW1, fb1, fW2, fb2,
                                          fW3, fb3, (float*)d_out);
}

// Round 18
// 451.978 us; speedup vs baseline: 1.0692x; 1.0307x over previous
//
#include <hip/hip_runtime.h>
#include <cmath>

// ---------------------------------------------------------------------------
// BrainAgeGATv2: 4-layer GATv2-ish GNN, N=40000 nodes, E=400000 edges, B=100
// graphs, hidden = H*C = 128.
// R14: 454.8us (BEST). gat chunk-8/lb(256,4)/VGPR36 = 49us, latency-bound
//      (traffic 107->49MB time-invariant x3; occupancy levers spill x2).
// R15: gat lb(128,8) regressed (spill). R16/R17: pool-fusion regressed
//      (global-atomic pool + per-call overhead > deleted kernel).
// R18: LOCK-IN -- exact R14 configuration restored.
// ---------------------------------------------------------------------------

#define CAP 48
#define POOL_SPLIT 8

typedef __bf16 bf16x8 __attribute__((ext_vector_type(8)));
typedef float f32x4 __attribute__((ext_vector_type(4)));

__device__ inline unsigned pack_bf16(__bf16 a, __bf16 b) {
  union { __bf16 h; unsigned short u; } ua, ub;
  ua.h = a; ub.h = b;
  return ((unsigned)ub.u << 16) | ua.u;
}

// ---------------- fused prep: ea_sum | embed | w_pack ------------------------
// blocks [0,Ge): ea_sum reduction; [Ge,Ge+Gn): embed; [Ge+Gn,+512): w_pack.

__global__ __launch_bounds__(256) void prep_kernel(
    const float* __restrict__ eattr, float* __restrict__ ea_sum, int E,
    const float* __restrict__ x, const float* __restrict__ W_emb,
    const float* __restrict__ b_emb, __bf16* __restrict__ h0hi,
    __bf16* __restrict__ h0lo, int n, const float* __restrict__ Wl1,
    const float* __restrict__ Wr1, const float* __restrict__ Wl234,
    const float* __restrict__ Wr234, __bf16* __restrict__ wfHi,
    __bf16* __restrict__ wfLo, int Ge, int Gn) {
  __shared__ float red[256];
  int bid = blockIdx.x;
  if (bid < Ge) {
    // ---- ea_sum ----
    int i = bid * 256 + threadIdx.x;
    float v = (i < E) ? eattr[i] : 0.f;
    red[threadIdx.x] = v;
    __syncthreads();
    for (int off = 128; off > 0; off >>= 1) {
      if (threadIdx.x < off) red[threadIdx.x] += red[threadIdx.x + off];
      __syncthreads();
    }
    if (threadIdx.x == 0) atomicAdd(ea_sum, red[0]);
    return;
  }
  bid -= Ge;
  if (bid < Gn) {
    // ---- embed: h0 = relu(x @ W_emb + b_emb) -> bf16 hi/lo ----
    int idx = bid * 256 + threadIdx.x;
    if (idx >= n * 64) return;
    int v = idx >> 6, j = idx & 63;
    float s = b_emb[j];
    s += x[v * 4 + 0] * W_emb[j];
    s += x[v * 4 + 1] * W_emb[64 + j];
    s += x[v * 4 + 2] * W_emb[128 + j];
    s += x[v * 4 + 3] * W_emb[192 + j];
    s = fmaxf(s, 0.f);
    __bf16 hi = (__bf16)s;
    h0hi[idx] = hi;
    h0lo[idx] = (__bf16)(s - (float)hi);
    return;
  }
  bid -= Gn;
  // ---- w_pack: per-lane MFMA fragment order ----
  // wf element (L, g, n, ks, lane l, e) = hi/lo of W[k][col], where
  // k = ks*32 + (l>>4)*8 + e, col = g*64 + n*16 + (l&15)  (W=[Wl|Wr], KxC).
  int k = bid & 127;
  int L = bid >> 7;
  int col = threadIdx.x;
  int K = (L == 0) ? 64 : 128;
  if (k >= K) return;
  int KS = K >> 5;
  const float* Wl = (L == 0) ? Wl1 : Wl234 + (size_t)(L - 1) * 128 * 128;
  const float* Wr = (L == 0) ? Wr1 : Wr234 + (size_t)(L - 1) * 128 * 128;
  float v = (col < 128) ? Wl[k * 128 + col] : Wr[k * 128 + (col - 128)];
  __bf16 hi = (__bf16)v;
  __bf16 lo = (__bf16)(v - (float)hi);
  int g = col >> 6, nn = (col >> 4) & 3, cl = col & 15;
  int ks = k >> 5, sl = (k >> 3) & 3, e = k & 7;
  int l = sl * 16 + cl;
  size_t dst =
      (size_t)L * 256 * 128 + ((((size_t)(g * 4 + nn) * KS + ks) * 64 + l) * 8 + e);
  wfHi[dst] = hi;
  wfLo[dst] = lo;
}

// fill padded CSR: row v occupies csr[v*CAP .. v*CAP+cnt[v])
__global__ __launch_bounds__(256) void fill_kernel(const int* __restrict__ ei,
                                                   const float* __restrict__ eattr,
                                                   const float* __restrict__ ea_sum,
                                                   int* __restrict__ cnt,
                                                   int2* __restrict__ csr, int E, int n) {
  int i = blockIdx.x * 256 + threadIdx.x;
  if (i >= E + n) return;
  int s, d;
  float ev;
  if (i < E) {
    s = ei[i];
    d = ei[(size_t)E + i];
    ev = eattr[i];
  } else {
    s = d = i - E;                       // self loop
    ev = ea_sum[0] * (1.0f / (float)E);  // mean(edge_attr)
  }
  int pos = atomicAdd(&cnt[d], 1);
  if (pos < CAP) csr[(size_t)d * CAP + pos] = make_int2(s, __float_as_int(ev));
}

// ---------------- MFMA GEMM v3: no LDS, no barrier ---------------------------
// Split-bf16 (3 terms). Block 64M x 64N (4 waves, wave w = rows 16w..16w+15).
// A fragments: direct coalesced global reads (rows partitioned across waves).
// W fragments: pre-packed global, same address across blocks (L2-hot).
// XCD-bijective swizzle co-locates the 4 N-blocks sharing an A-panel.
// xl (cols 0-127) and xr (cols 128-255) both emitted as bf16.
// Fragment mapping (m89/m101-verified): a: lane l -> A[l%16][8*(l>>4)+e];
// b: lane l -> B[8*(l>>4)+e][l%16]; d: lane l, reg r -> D[4*(l>>4)+r][l%16].

__global__ __launch_bounds__(256) void gemm_mfma_kernel(
    const __bf16* __restrict__ hA, const __bf16* __restrict__ lA,
    const __bf16* __restrict__ wfHi, const __bf16* __restrict__ wfLo,
    const float* __restrict__ bl_l, const float* __restrict__ br_l,
    __bf16* __restrict__ xlb, __bf16* __restrict__ xrb, int K) {
  int t = threadIdx.x;
  // bijective XCD swizzle (m204): consecutive work ids -> same XCD
  int nwg = gridDim.x;
  int bid = blockIdx.x;
  int q8 = nwg >> 3, r8 = nwg & 7;
  int xcd = bid & 7, slot = bid >> 3;
  int wid = (xcd < r8 ? xcd * (q8 + 1) : r8 * (q8 + 1) + (xcd - r8) * q8) + slot;
  int g = wid & 3;           // 64-col slab (4 siblings share the A-panel)
  int n0 = g << 6;
  int r0 = (wid >> 2) << 6;  // M-tile
  int KS = K >> 5;

  int w = t >> 6, lane = t & 63;
  int arow = r0 + (w << 4) + (lane & 15);
  int kbb = (lane >> 4) << 4;  // byte offset of this lane's k-group in A row
  const char* pAhiG = (const char*)hA + (size_t)arow * (K << 1) + kbb;
  const char* pAloG = (const char*)lA + (size_t)arow * (K << 1) + kbb;
  const __bf16* wfH = wfHi + (size_t)(g * 4) * KS * 512 + lane * 8;
  const __bf16* wfL = wfLo + (size_t)(g * 4) * KS * 512 + lane * 8;

  f32x4 acc[4];
#pragma unroll
  for (int n = 0; n < 4; n++) acc[n] = (f32x4){0.f, 0.f, 0.f, 0.f};

  union U { uint4 u; bf16x8 b; };
  for (int ks = 0; ks < KS; ks++) {
    U ahi, alo;
    ahi.u = *(const uint4*)(pAhiG + (ks << 6));  // 64B per 32-k step
    alo.u = *(const uint4*)(pAloG + (ks << 6));
#pragma unroll
    for (int n = 0; n < 4; n++) {
      int wo = (n * KS + ks) << 9;  // *512 elements
      U bhi, blo;
      bhi.u = *(const uint4*)(wfH + wo);
      blo.u = *(const uint4*)(wfL + wo);
      acc[n] = __builtin_amdgcn_mfma_f32_16x16x32_bf16(ahi.b, bhi.b, acc[n], 0, 0, 0);
      acc[n] = __builtin_amdgcn_mfma_f32_16x16x32_bf16(ahi.b, blo.b, acc[n], 0, 0, 0);
      acc[n] = __builtin_amdgcn_mfma_f32_16x16x32_bf16(alo.b, bhi.b, acc[n], 0, 0, 0);
    }
  }

#pragma unroll
  for (int n = 0; n < 4; n++) {
    int col = n0 + (n << 4) + (lane & 15);
    float bv = (n0 < 128) ? bl_l[col & 127] : br_l[col & 127];
#pragma unroll
    for (int r = 0; r < 4; r++) {
      int row = r0 + (w << 4) + ((lane >> 4) << 2) + r;
      float val = acc[n][r] + bv;
      if (n0 < 128)
        xlb[(size_t)row * 128 + col] = (__bf16)val;
      else
        xrb[(size_t)row * 128 + (col - 128)] = (__bf16)val;
    }
  }
}

// ---------------- GAT aggregation: R14-verified chunk-8, lb(256,4), FROZEN ---

#define GAT_CHUNK 8

__global__ __launch_bounds__(256, 4) void gat_kernel(
    const __bf16* __restrict__ xlb, const __bf16* __restrict__ xrb,
    const int* __restrict__ cnt, const int2* __restrict__ csr,
    const float* __restrict__ We_l, const float* __restrict__ att_l,
    const float* __restrict__ bo_l, float* __restrict__ z, int n) {
  int wave = threadIdx.x >> 6;
  int lane = threadIdx.x & 63;
  int v = blockIdx.x * 4 + wave;
  if (v >= n) return;

  int c = lane * 2;  // channels c, c+1; head = c/16 = lane/8
  unsigned pxr = *reinterpret_cast<const unsigned*>(xrb + (size_t)v * 128 + c);
  float2 xrv;
  xrv.x = __uint_as_float(pxr << 16);
  xrv.y = __uint_as_float(pxr & 0xffff0000u);
  float2 wev = *reinterpret_cast<const float2*>(We_l + c);
  float2 atv = *reinterpret_cast<const float2*>(att_l + c);

  float m = -INFINITY, d = 0.f;
  float acc0 = 0.f, acc1 = 0.f;

  int beg = v * CAP;
  int end = beg + min(cnt[v], CAP);
  for (int base = beg; base < end; base += GAT_CHUNK) {
    int cnt8 = min(GAT_CHUNK, end - base);
    // wave-uniform metadata loads: all lanes hit the same cacheline
    int2 md[GAT_CHUNK];
#pragma unroll
    for (int j = 0; j < GAT_CHUNK; j++) {
      if (j >= cnt8) break;
      md[j] = csr[base + j];
    }
    // bf16x2 gathers, issued back-to-back (independent)
    float2 a[GAT_CHUNK];
#pragma unroll
    for (int j = 0; j < GAT_CHUNK; j++) {
      if (j >= cnt8) break;
      unsigned p = *reinterpret_cast<const unsigned*>(xlb + (size_t)md[j].x * 128 + c);
      a[j].x = __uint_as_float(p << 16);
      a[j].y = __uint_as_float(p & 0xffff0000u);
    }
    // scores: leaky_relu -> att dot -> 8-lane head reduce (3 shfl steps)
    float q[GAT_CHUNK];
#pragma unroll
    for (int j = 0; j < GAT_CHUNK; j++) {
      if (j >= cnt8) break;
      float ee = __int_as_float(md[j].y);
      float t0 = a[j].x + xrv.x + ee * wev.x;
      float t1 = a[j].y + xrv.y + ee * wev.y;
      t0 = (t0 >= 0.f) ? t0 : 0.2f * t0;  // leaky_relu
      t1 = (t1 >= 0.f) ? t1 : 0.2f * t1;
      float qq = t0 * atv.x + t1 * atv.y;
#pragma unroll
      for (int off = 1; off < 8; off <<= 1) qq += __shfl_xor(qq, off);
      q[j] = qq;
    }
    // chunk max + single rescale (exact exp(s - smax) semantics)
    float cm = -INFINITY;
#pragma unroll
    for (int j = 0; j < GAT_CHUNK; j++) {
      if (j >= cnt8) break;
      cm = fmaxf(cm, q[j]);
    }
    float nm = fmaxf(m, cm);
    float sc = __expf(m - nm);  // exp(-inf)=0 on the first chunk
    d *= sc;
    acc0 *= sc;
    acc1 *= sc;
#pragma unroll
    for (int j = 0; j < GAT_CHUNK; j++) {
      if (j >= cnt8) break;
      float e = __expf(q[j] - nm);
      d += e;
      acc0 += e * a[j].x;
      acc1 += e * a[j].y;
    }
    m = nm;
  }
  float inv = 1.f / (d + 1e-16f);
  float2 o;
  o.x = acc0 * inv + bo_l[c];
  o.y = acc1 * inv + bo_l[c + 1];
  *reinterpret_cast<float2*>(z + (size_t)v * 128 + c) = o;
}

// ---------------- BN: stats (float2) + final fused into apply ----------------

__global__ __launch_bounds__(256) void bn_stats_kernel(const float2* __restrict__ z2,
                                                       float* __restrict__ stats, int n) {
  int cp = threadIdx.x & 63;       // channel pair
  int quarter = threadIdx.x >> 6;  // 4 rows in parallel
  int chunk = (n + gridDim.x - 1) / gridDim.x;
  int v0 = blockIdx.x * chunk;
  int v1 = min(v0 + chunk, n);
  float s0 = 0.f, s1 = 0.f, q0 = 0.f, q1 = 0.f;
  for (int v = v0 + quarter; v < v1; v += 4) {
    float2 val = z2[(size_t)v * 64 + cp];
    s0 += val.x;
    q0 += val.x * val.x;
    s1 += val.y;
    q1 += val.y * val.y;
  }
  __shared__ float ls[4][128], lq[4][128];
  ls[quarter][cp * 2] = s0;
  ls[quarter][cp * 2 + 1] = s1;
  lq[quarter][cp * 2] = q0;
  lq[quarter][cp * 2 + 1] = q1;
  __syncthreads();
  if (threadIdx.x < 128) {
    int c = threadIdx.x;
    atomicAdd(&stats[c], ls[0][c] + ls[1][c] + ls[2][c] + ls[3][c]);
    atomicAdd(&stats[128 + c], lq[0][c] + lq[1][c] + lq[2][c] + lq[3][c]);
  }
}

__global__ __launch_bounds__(256) void bn_apply_kernel(
    const float2* __restrict__ z2, const float* __restrict__ stats_l,
    const float* __restrict__ gamma_l, const float* __restrict__ beta_l,
    unsigned* __restrict__ hhi2, unsigned* __restrict__ hlo2, int add_res, int n) {
  int i = blockIdx.x * 256 + threadIdx.x;  // channel-pair index
  if (i >= n * 64) return;
  int cp = (i & 63) * 2;
  float mean0 = stats_l[cp] / (float)n;
  float var0 = stats_l[128 + cp] / (float)n - mean0 * mean0;
  float sc0 = gamma_l[cp] * rsqrtf(var0 + 1e-5f);
  float off0 = beta_l[cp] - mean0 * sc0;
  float mean1 = stats_l[cp + 1] / (float)n;
  float var1 = stats_l[128 + cp + 1] / (float)n - mean1 * mean1;
  float sc1 = gamma_l[cp + 1] * rsqrtf(var1 + 1e-5f);
  float off1 = beta_l[cp + 1] - mean1 * sc1;

  float2 zz = z2[i];
  float v0 = zz.x * sc0 + off0;
  float v1 = zz.y * sc1 + off1;
  if (add_res) {
    unsigned ph = hhi2[i], pl = hlo2[i];
    v0 += __uint_as_float(ph << 16) + __uint_as_float(pl << 16);
    v1 += __uint_as_float(ph & 0xffff0000u) + __uint_as_float(pl & 0xffff0000u);
  }
  v0 = fmaxf(v0, 0.f);
  v1 = fmaxf(v1, 0.f);
  __bf16 h0 = (__bf16)v0, h1 = (__bf16)v1;
  __bf16 l0 = (__bf16)(v0 - (float)h0), l1 = (__bf16)(v1 - (float)h1);
  hhi2[i] = pack_bf16(h0, h1);
  hlo2[i] = pack_bf16(l0, l1);
}

// ---------------- pooling, two-stage (batch = repeat(arange(B), N/B)) --------

__global__ __launch_bounds__(256) void pool_partial_kernel(
    const unsigned* __restrict__ hhi2, const unsigned* __restrict__ hlo2,
    float* __restrict__ part, int npg) {
  int b = blockIdx.x, q = blockIdx.y;
  int half = threadIdx.x >> 6;  // 0..3 (4 rows in parallel)
  int cp = threadIdx.x & 63;    // channel pair
  int rows = npg / POOL_SPLIT;
  size_t base = ((size_t)b * npg + (size_t)q * rows) * 64;
  float s0 = 0.f, s1 = 0.f;
  for (int r = half; r < rows; r += 4) {
    unsigned uh = hhi2[base + (size_t)r * 64 + cp];
    unsigned ul = hlo2[base + (size_t)r * 64 + cp];
    s0 += __uint_as_float(uh << 16) + __uint_as_float(ul << 16);
    s1 += __uint_as_float(uh & 0xffff0000u) + __uint_as_float(ul & 0xffff0000u);
  }
  __shared__ float ls[4][128];
  ls[half][cp * 2] = s0;
  ls[half][cp * 2 + 1] = s1;
  __syncthreads();
  if (threadIdx.x < 128) {
    int c = threadIdx.x;
    part[((size_t)b * POOL_SPLIT + q) * 128 + c] =
        ls[0][c] + ls[1][c] + ls[2][c] + ls[3][c];
  }
}

// ---------------- fused MLP head ---------------------------------------------

__global__ __launch_bounds__(128) void final_mlp_kernel(
    const float* __restrict__ part, float inv_npg, const float* __restrict__ gf,
    const float* __restrict__ mW1, const float* __restrict__ mb1,
    const float* __restrict__ mW2, const float* __restrict__ mb2,
    const float* __restrict__ gW1, const float* __restrict__ gb1,
    const float* __restrict__ gW2, const float* __restrict__ gb2,
    const float* __restrict__ fW1, const float* __restrict__ fb1,
    const float* __restrict__ fW2, const float* __restrict__ fb2,
    const float* __restrict__ fW3, const float* __restrict__ fb3,
    float* __restrict__ out) {
  int b = blockIdx.x, t = threadIdx.x;
  __shared__ float s1[16], s2[16], s1b[16], s2b[16];
  __shared__ float zv[160], t1[128], t2[64];

  if (t < 16) {
    float s = mb1[t];
    for (int i = 0; i < 4; i++) s += gf[b * 6 + i] * mW1[i * 16 + t];
    s1[t] = fmaxf(s, 0.f);
  } else if (t < 32) {
    int j = t - 16;
    float s = gb1[j];
    for (int i = 0; i < 2; i++) s += gf[b * 6 + 4 + i] * gW1[i * 16 + j];
    s2[j] = fmaxf(s, 0.f);
  }
  {
    float ps = 0.f;
#pragma unroll
    for (int q = 0; q < POOL_SPLIT; q++)
      ps += part[((size_t)b * POOL_SPLIT + q) * 128 + t];
    zv[t] = ps * inv_npg;
  }
  __syncthreads();
  if (t < 16) {
    float s = mb2[t];
    for (int i = 0; i < 16; i++) s += s1[i] * mW2[i * 16 + t];
    s1b[t] = fmaxf(s, 0.f);
  } else if (t < 32) {
    int j = t - 16;
    float s = gb2[j];
    for (int i = 0; i < 16; i++) s += s2[i] * gW2[i * 16 + j];
    s2b[j] = fmaxf(s, 0.f);
  }
  __syncthreads();
  if (t < 16)
    zv[128 + t] = s1b[t];
  else if (t < 32)
    zv[128 + t] = s2b[t - 16];
  __syncthreads();
  {
    float s = fb1[t];
    for (int i = 0; i < 160; i++) s += zv[i] * fW1[i * 128 + t];
    t1[t] = fmaxf(s, 0.f);
  }
  __syncthreads();
  if (t < 64) {
    float s = fb2[t];
    for (int i = 0; i < 128; i++) s += t1[i] * fW2[i * 64 + t];
    t2[t] = fmaxf(s, 0.f);
  }
  __syncthreads();
  if (t == 0) {
    float s = fb3[0];
    for (int i = 0; i < 64; i++) s += t2[i] * fW3[i];
    out[b] = s;
  }
}

// ---------------- host launcher ----------------------------------------------

extern "C" void kernel_launch(void* const* d_in, const int* in_sizes, int n_in,
                              void* d_out, int out_size, void* d_ws, size_t ws_size,
                              hipStream_t stream) {
  const float* x = (const float*)d_in[0];
  const int* ei = (const int*)d_in[1];
  const float* eattr = (const float*)d_in[2];
  const float* gf = (const float*)d_in[4];
  const float* W_emb = (const float*)d_in[5];
  const float* b_emb = (const float*)d_in[6];
  const float* Wl1 = (const float*)d_in[7];
  const float* Wr1 = (const float*)d_in[8];
  const float* Wl234 = (const float*)d_in[9];
  const float* Wr234 = (const float*)d_in[10];
  const float* bl = (const float*)d_in[11];
  const float* br = (const float*)d_in[12];
  const float* We = (const float*)d_in[13];
  const float* att = (const float*)d_in[14];
  const float* bo = (const float*)d_in[15];
  const float* gamma = (const float*)d_in[16];
  const float* beta = (const float*)d_in[17];
  const float* mW1 = (const float*)d_in[18];
  const float* mb1 = (const float*)d_in[19];
  const float* mW2 = (const float*)d_in[20];
  const float* mb2 = (const float*)d_in[21];
  const float* gW1 = (const float*)d_in[22];
  const float* gb1 = (const float*)d_in[23];
  const float* gW2 = (const float*)d_in[24];
  const float* gb2 = (const float*)d_in[25];
  const float* fW1 = (const float*)d_in[26];
  const float* fb1 = (const float*)d_in[27];
  const float* fW2 = (const float*)d_in[28];
  const float* fb2 = (const float*)d_in[29];
  const float* fW3 = (const float*)d_in[30];
  const float* fb3 = (const float*)d_in[31];

  const int N = in_sizes[0] / 4;
  const int E = in_sizes[2];
  const int B = in_sizes[4] / 6;
  const int Ge = (E + 255) / 256;
  const int Gn = (N * 64 + 255) / 256;

  char* wsb = (char*)d_ws;
  size_t off = 0;
  auto alloc = [&](size_t bytes) {
    size_t r = off;
    off += (bytes + 255) & ~(size_t)255;
    return r;
  };
  // NOTE: cnt, ea_sum, stats contiguous -> single upfront memset.
  int* cnt = (int*)(wsb + alloc((size_t)N * 4));  // N*4 = 160000 (256-mult)
  float* ea_sum = (float*)(wsb + alloc(256));
  float* stats = (float*)(wsb + alloc(4 * 256 * 4));  // [L][256]
  size_t zero_bytes = (size_t)N * 4 + 256 + 4 * 256 * 4;

  float* z = (float*)(wsb + alloc((size_t)N * 128 * 4));
  __bf16* xrb = (__bf16*)(wsb + alloc((size_t)N * 128 * 2));
  __bf16* xlb = (__bf16*)(wsb + alloc((size_t)N * 128 * 2));
  __bf16* hhi = (__bf16*)(wsb + alloc((size_t)N * 128 * 2));
  __bf16* hlo = (__bf16*)(wsb + alloc((size_t)N * 128 * 2));
  __bf16* h0hi = (__bf16*)(wsb + alloc((size_t)N * 64 * 2));
  __bf16* h0lo = (__bf16*)(wsb + alloc((size_t)N * 64 * 2));
  __bf16* wfHi = (__bf16*)(wsb + alloc((size_t)4 * 256 * 128 * 2));
  __bf16* wfLo = (__bf16*)(wsb + alloc((size_t)4 * 256 * 128 * 2));
  int2* csr = (int2*)(wsb + alloc((size_t)N * CAP * 8));
  float* part = (float*)(wsb + alloc((size_t)B * POOL_SPLIT * 128 * 4));
  (void)ws_size;
  (void)n_in;
  (void)out_size;

  // ---- memset + fused prep (ea_sum | embed | w_pack) + CSR fill ----
  hipMemsetAsync(cnt, 0, zero_bytes, stream);
  prep_kernel<<<Ge + Gn + 512, 256, 0, stream>>>(eattr, ea_sum, E, x, W_emb, b_emb,
                                                 h0hi, h0lo, N, Wl1, Wr1, Wl234, Wr234,
                                                 wfHi, wfLo, Ge, Gn);
  fill_kernel<<<(E + N + 255) / 256, 256, 0, stream>>>(ei, eattr, ea_sum, cnt, csr, E,
                                                       N);

  // ---- 4 GAT layers ----
  for (int L = 0; L < 4; ++L) {
    int K = (L == 0) ? 64 : 128;
    const __bf16* hA = (L == 0) ? h0hi : hhi;
    const __bf16* lA = (L == 0) ? h0lo : hlo;

    gemm_mfma_kernel<<<4 * (N / 64), 256, 0, stream>>>(
        hA, lA, wfHi + (size_t)L * 256 * 128, wfLo + (size_t)L * 256 * 128,
        bl + L * 128, br + L * 128, xlb, xrb, K);
    gat_kernel<<<(N + 3) / 4, 256, 0, stream>>>(xlb, xrb, cnt, csr, We + L * 128,
                                                att + L * 128, bo + L * 128, z, N);
    bn_stats_kernel<<<256, 256, 0, stream>>>((const float2*)z, stats + L * 256, N);
    bn_apply_kernel<<<(N * 64 + 255) / 256, 256, 0, stream>>>(
        (const float2*)z, stats + L * 256, gamma + L * 128, beta + L * 128,
        (unsigned*)hhi, (unsigned*)hlo, (L == 0) ? 0 : 1, N);
  }

  // ---- pool + head ----
  pool_partial_kernel<<<dim3(B, POOL_SPLIT), 256, 0, stream>>>(
      (const unsigned*)hhi, (const unsigned*)hlo, part, N / B);
  final_mlp_kernel<<<B, 128, 0, stream>>>(part, (float)B / (float)N, gf, mW1, mb1, mW2,
                                          mb2, gW1, gb1, gW2, gb2, fW1, fb1, fW2, fb2,
                                          fW3, fb3, (float*)d_out);
}